// Round 1
// baseline (895.972 us; speedup 1.0000x reference)
//
#include <hip/hip_runtime.h>
#include <math.h>

#define DM    1024
#define DQK   128
#define BATCH 4
#define SEQ   4096
#define SCALE 0.08838834764831845f   // 1/sqrt(128)

// ---------------- QKV projection ----------------
// out[M][128] = x[M][1024] @ W[1024][128] + b
// grid (M/64, 3), block 128 threads. Tile 64 rows x 128 cols, 8x8 micro-tile.
// x chunk staged TRANSPOSED in LDS (K-major) so operand reads are float4.
// W streamed straight from global (512 KB, L2-resident).
__global__ __launch_bounds__(128) void proj_kernel(
    const float* __restrict__ x,
    const float* __restrict__ Wq, const float* __restrict__ bq,
    const float* __restrict__ Wk, const float* __restrict__ bk,
    const float* __restrict__ Wv, const float* __restrict__ bv,
    float* __restrict__ qo, float* __restrict__ ko, float* __restrict__ vo)
{
    const float* __restrict__ W;
    const float* __restrict__ bias;
    float* __restrict__ out;
    if (blockIdx.y == 0)      { W = Wq; bias = bq; out = qo; }
    else if (blockIdx.y == 1) { W = Wk; bias = bk; out = ko; }
    else                      { W = Wv; bias = bv; out = vo; }

    __shared__ float xst[32][68];   // [kk][row] transposed, pad 68 (16B-aligned rows)

    const int tid  = threadIdx.x;
    const int ty   = tid >> 4;      // 0..7  -> 8 rows each
    const int tx   = tid & 15;      // 0..15 -> 8 cols each
    const int row0 = blockIdx.x * 64;

    float acc[8][8];
    #pragma unroll
    for (int i = 0; i < 8; ++i)
        #pragma unroll
        for (int j = 0; j < 8; ++j) acc[i][j] = 0.f;

    for (int k0 = 0; k0 < DM; k0 += 32) {
        __syncthreads();
        // stage x tile 64 rows x 32 K, transposed: 512 float4 / 128 threads = 4 each
        #pragma unroll
        for (int it = 0; it < 4; ++it) {
            int idx = tid + it * 128;
            int r   = idx >> 3;       // 0..63
            int c4  = idx & 7;        // 0..7
            float4 t = *(const float4*)(x + (size_t)(row0 + r) * DM + k0 + c4 * 4);
            xst[c4 * 4 + 0][r] = t.x;
            xst[c4 * 4 + 1][r] = t.y;
            xst[c4 * 4 + 2][r] = t.z;
            xst[c4 * 4 + 3][r] = t.w;
        }
        __syncthreads();

        #pragma unroll
        for (int kk = 0; kk < 32; ++kk) {
            float4 a0 = *(const float4*)&xst[kk][ty * 8];
            float4 a1 = *(const float4*)&xst[kk][ty * 8 + 4];
            const float* wrow = W + (size_t)(k0 + kk) * DQK + tx * 8;
            float4 b0 = *(const float4*)(wrow);
            float4 b1 = *(const float4*)(wrow + 4);
            float av[8] = {a0.x, a0.y, a0.z, a0.w, a1.x, a1.y, a1.z, a1.w};
            float bw[8] = {b0.x, b0.y, b0.z, b0.w, b1.x, b1.y, b1.z, b1.w};
            #pragma unroll
            for (int i = 0; i < 8; ++i)
                #pragma unroll
                for (int j = 0; j < 8; ++j)
                    acc[i][j] = fmaf(av[i], bw[j], acc[i][j]);
        }
    }

    // bias + store
    float4 bb0 = *(const float4*)(bias + tx * 8);
    float4 bb1 = *(const float4*)(bias + tx * 8 + 4);
    float bvals[8] = {bb0.x, bb0.y, bb0.z, bb0.w, bb1.x, bb1.y, bb1.z, bb1.w};
    #pragma unroll
    for (int i = 0; i < 8; ++i) {
        int r = row0 + ty * 8 + i;
        float4 o0 = make_float4(acc[i][0] + bvals[0], acc[i][1] + bvals[1],
                                acc[i][2] + bvals[2], acc[i][3] + bvals[3]);
        float4 o1 = make_float4(acc[i][4] + bvals[4], acc[i][5] + bvals[5],
                                acc[i][6] + bvals[6], acc[i][7] + bvals[7]);
        *(float4*)(out + (size_t)r * DQK + tx * 8)     = o0;
        *(float4*)(out + (size_t)r * DQK + tx * 8 + 4) = o1;
    }
}

// ---------------- Flash attention ----------------
// grid (SEQ/64, BATCH), block 256 threads. Q-tile 64 rows/block; K/V tiles of 64.
// Q and K staged K-major (transposed) in LDS; P staged transposed for float4 PV reads.
__global__ __launch_bounds__(256) void attn_kernel(
    const float* __restrict__ qg, const float* __restrict__ kg,
    const float* __restrict__ vg, float* __restrict__ out)
{
    __shared__ float qt [128][68];   // qt[kk][qr]  (pre-scaled by SCALE)
    __shared__ float ktl[128][68];   // ktl[kk][kr]
    __shared__ float vs [64][132];   // vs[kr][c]
    __shared__ float pst[64][68];    // pst[kr][qr]

    const int tid = threadIdx.x;
    const int ty  = tid >> 4;        // 0..15 -> 4 q-rows each
    const int tx  = tid & 15;        // 0..15 -> 4 k-cols (scores) / 8 v-cols (PV)
    const int b   = blockIdx.y;
    const int q0  = blockIdx.x * 64;

    const float* qb = qg + (size_t)b * SEQ * DQK;
    const float* kb = kg + (size_t)b * SEQ * DQK;
    const float* vb = vg + (size_t)b * SEQ * DQK;

    // stage Q transposed (+ fold in the 1/sqrt(d) scale): 2048 float4 / 256 thr = 8 each
    #pragma unroll
    for (int it = 0; it < 8; ++it) {
        int idx = tid + it * 256;
        int r   = idx >> 5;          // 0..63
        int c4  = idx & 31;          // 0..31
        float4 t = *(const float4*)(qb + (size_t)(q0 + r) * DQK + c4 * 4);
        qt[c4 * 4 + 0][r] = t.x * SCALE;
        qt[c4 * 4 + 1][r] = t.y * SCALE;
        qt[c4 * 4 + 2][r] = t.z * SCALE;
        qt[c4 * 4 + 3][r] = t.w * SCALE;
    }

    float m_run[4], l_run[4], o_acc[4][8];
    #pragma unroll
    for (int i = 0; i < 4; ++i) {
        m_run[i] = -1e30f;
        l_run[i] = 0.f;
        #pragma unroll
        for (int j = 0; j < 8; ++j) o_acc[i][j] = 0.f;
    }

    for (int kt = 0; kt < SEQ / 64; ++kt) {
        __syncthreads();   // protect ktl/vs (prev PV) and pst (prev PV reads)
        // stage K transposed + V row-major
        #pragma unroll
        for (int it = 0; it < 8; ++it) {
            int idx = tid + it * 256;
            int r   = idx >> 5;
            int c4  = idx & 31;
            float4 t = *(const float4*)(kb + (size_t)(kt * 64 + r) * DQK + c4 * 4);
            ktl[c4 * 4 + 0][r] = t.x;
            ktl[c4 * 4 + 1][r] = t.y;
            ktl[c4 * 4 + 2][r] = t.z;
            ktl[c4 * 4 + 3][r] = t.w;
            float4 u = *(const float4*)(vb + (size_t)(kt * 64 + r) * DQK + c4 * 4);
            *(float4*)&vs[r][c4 * 4] = u;
        }
        __syncthreads();

        // scores: s[i][j] = sum_kk qt[kk][ty*4+i] * ktl[kk][tx*4+j]  (scale folded into qt)
        float s[4][4];
        #pragma unroll
        for (int i = 0; i < 4; ++i)
            #pragma unroll
            for (int j = 0; j < 4; ++j) s[i][j] = 0.f;

        #pragma unroll 8
        for (int kk = 0; kk < DQK; ++kk) {
            float4 a = *(const float4*)&qt[kk][ty * 4];
            float4 c = *(const float4*)&ktl[kk][tx * 4];
            float avv[4] = {a.x, a.y, a.z, a.w};
            float cvv[4] = {c.x, c.y, c.z, c.w};
            #pragma unroll
            for (int i = 0; i < 4; ++i)
                #pragma unroll
                for (int j = 0; j < 4; ++j)
                    s[i][j] = fmaf(avv[i], cvv[j], s[i][j]);
        }

        // online softmax update (row groups share ty; reduce across 16 tx lanes)
        float alpha[4];
        float p[4][4];
        #pragma unroll
        for (int i = 0; i < 4; ++i) {
            float rmax = fmaxf(fmaxf(s[i][0], s[i][1]), fmaxf(s[i][2], s[i][3]));
            #pragma unroll
            for (int msk = 1; msk < 16; msk <<= 1)
                rmax = fmaxf(rmax, __shfl_xor(rmax, msk, 16));
            float m_new = fmaxf(m_run[i], rmax);
            alpha[i] = __expf(m_run[i] - m_new);
            float rsum = 0.f;
            #pragma unroll
            for (int j = 0; j < 4; ++j) {
                p[i][j] = __expf(s[i][j] - m_new);
                rsum += p[i][j];
            }
            #pragma unroll
            for (int msk = 1; msk < 16; msk <<= 1)
                rsum += __shfl_xor(rsum, msk, 16);
            l_run[i] = l_run[i] * alpha[i] + rsum;
            m_run[i] = m_new;
            #pragma unroll
            for (int j = 0; j < 8; ++j) o_acc[i][j] *= alpha[i];
        }

        // stage P transposed: pst[kcol][qrow]
        #pragma unroll
        for (int i = 0; i < 4; ++i)
            #pragma unroll
            for (int j = 0; j < 4; ++j)
                pst[tx * 4 + j][ty * 4 + i] = p[i][j];
        __syncthreads();

        // PV: o_acc[i][j] += sum_kidx pst[kidx][ty*4+i] * vs[kidx][tx*8+j]
        #pragma unroll 8
        for (int kidx = 0; kidx < 64; ++kidx) {
            float4 pv = *(const float4*)&pst[kidx][ty * 4];
            float4 v0 = *(const float4*)&vs[kidx][tx * 8];
            float4 v1 = *(const float4*)&vs[kidx][tx * 8 + 4];
            float pa[4] = {pv.x, pv.y, pv.z, pv.w};
            float vv[8] = {v0.x, v0.y, v0.z, v0.w, v1.x, v1.y, v1.z, v1.w};
            #pragma unroll
            for (int i = 0; i < 4; ++i)
                #pragma unroll
                for (int j = 0; j < 8; ++j)
                    o_acc[i][j] = fmaf(pa[i], vv[j], o_acc[i][j]);
        }
    }

    // epilogue: divide by softmax denom, store
    #pragma unroll
    for (int i = 0; i < 4; ++i) {
        float inv = 1.0f / l_run[i];
        int r = q0 + ty * 4 + i;
        float4 o0 = make_float4(o_acc[i][0] * inv, o_acc[i][1] * inv,
                                o_acc[i][2] * inv, o_acc[i][3] * inv);
        float4 o1 = make_float4(o_acc[i][4] * inv, o_acc[i][5] * inv,
                                o_acc[i][6] * inv, o_acc[i][7] * inv);
        float* orow = out + ((size_t)b * SEQ + r) * DQK + tx * 8;
        *(float4*)(orow)     = o0;
        *(float4*)(orow + 4) = o1;
    }
}

extern "C" void kernel_launch(void* const* d_in, const int* in_sizes, int n_in,
                              void* d_out, int out_size, void* d_ws, size_t ws_size,
                              hipStream_t stream) {
    const float* x  = (const float*)d_in[0];
    const float* Wq = (const float*)d_in[1];
    const float* bq = (const float*)d_in[2];
    const float* Wk = (const float*)d_in[3];
    const float* bk = (const float*)d_in[4];
    const float* Wv = (const float*)d_in[5];
    const float* bv = (const float*)d_in[6];
    float* outp = (float*)d_out;

    float* q = (float*)d_ws;                       // 4*4096*128 fp32 = 8 MB
    float* k = q + (size_t)BATCH * SEQ * DQK;      // 8 MB
    float* v = k + (size_t)BATCH * SEQ * DQK;      // 8 MB

    dim3 pgrid(BATCH * SEQ / 64, 3);
    proj_kernel<<<pgrid, 128, 0, stream>>>(x, Wq, bq, Wk, bk, Wv, bv, q, k, v);

    dim3 agrid(SEQ / 64, BATCH);
    attn_kernel<<<agrid, 256, 0, stream>>>(q, k, v, outp);
}

// Round 2
// 334.506 us; speedup vs baseline: 2.6785x; 2.6785x over previous
//
#include <hip/hip_runtime.h>
#include <math.h>

#define DM    1024
#define DQK   128
#define BATCH 4
#define SEQ   4096
// 1/sqrt(128) * log2(e) folded into q at proj time -> softmax uses exp2 directly
#define QSCALE (0.08838834764831845f * 1.4426950408889634f)

typedef _Float16 f16;
typedef _Float16 f16x8 __attribute__((ext_vector_type(8)));
typedef float    f32x4 __attribute__((ext_vector_type(4)));

// ---------------- QKV projection (fp32 compute, f16 outputs) ----------------
// out[M][128] = x[M][1024] @ W[1024][128] + b ; q scaled by QSCALE; v stored transposed [b][d][s]
__global__ __launch_bounds__(128) void proj_kernel(
    const float* __restrict__ x,
    const float* __restrict__ Wq, const float* __restrict__ bq,
    const float* __restrict__ Wk, const float* __restrict__ bk,
    const float* __restrict__ Wv, const float* __restrict__ bv,
    f16* __restrict__ qo, f16* __restrict__ ko, f16* __restrict__ vto)
{
    const float* __restrict__ W;
    const float* __restrict__ bias;
    if (blockIdx.y == 0)      { W = Wq; bias = bq; }
    else if (blockIdx.y == 1) { W = Wk; bias = bk; }
    else                      { W = Wv; bias = bv; }

    __shared__ float xst[32][68];   // x tile transposed [k][row]

    const int tid  = threadIdx.x;
    const int ty   = tid >> 4;      // 0..7
    const int tx   = tid & 15;      // 0..15
    const int row0 = blockIdx.x * 64;

    float acc[8][8];
    #pragma unroll
    for (int i = 0; i < 8; ++i)
        #pragma unroll
        for (int j = 0; j < 8; ++j) acc[i][j] = 0.f;

    for (int k0 = 0; k0 < DM; k0 += 32) {
        __syncthreads();
        #pragma unroll
        for (int it = 0; it < 4; ++it) {
            int idx = tid + it * 128;
            int r   = idx >> 3;
            int c4  = idx & 7;
            float4 t = *(const float4*)(x + (size_t)(row0 + r) * DM + k0 + c4 * 4);
            xst[c4 * 4 + 0][r] = t.x;
            xst[c4 * 4 + 1][r] = t.y;
            xst[c4 * 4 + 2][r] = t.z;
            xst[c4 * 4 + 3][r] = t.w;
        }
        __syncthreads();

        #pragma unroll
        for (int kk = 0; kk < 32; ++kk) {
            float4 a0 = *(const float4*)&xst[kk][ty * 8];
            float4 a1 = *(const float4*)&xst[kk][ty * 8 + 4];
            const float* wrow = W + (size_t)(k0 + kk) * DQK + tx * 8;
            float4 b0 = *(const float4*)(wrow);
            float4 b1 = *(const float4*)(wrow + 4);
            float av[8] = {a0.x, a0.y, a0.z, a0.w, a1.x, a1.y, a1.z, a1.w};
            float bw[8] = {b0.x, b0.y, b0.z, b0.w, b1.x, b1.y, b1.z, b1.w};
            #pragma unroll
            for (int i = 0; i < 8; ++i)
                #pragma unroll
                for (int j = 0; j < 8; ++j)
                    acc[i][j] = fmaf(av[i], bw[j], acc[i][j]);
        }
    }

    float bvals[8];
    {
        float4 bb0 = *(const float4*)(bias + tx * 8);
        float4 bb1 = *(const float4*)(bias + tx * 8 + 4);
        bvals[0]=bb0.x; bvals[1]=bb0.y; bvals[2]=bb0.z; bvals[3]=bb0.w;
        bvals[4]=bb1.x; bvals[5]=bb1.y; bvals[6]=bb1.z; bvals[7]=bb1.w;
    }

    if (blockIdx.y == 2) {
        // vT[b][d][s]
        int gb = row0 >> 12;
        int s0 = (row0 & (SEQ - 1)) + ty * 8;
        #pragma unroll
        for (int j = 0; j < 8; ++j) {
            f16x8 pk;
            #pragma unroll
            for (int i = 0; i < 8; ++i) pk[i] = (f16)(acc[i][j] + bvals[j]);
            *(f16x8*)(vto + ((size_t)gb * DQK + tx * 8 + j) * SEQ + s0) = pk;
        }
    } else {
        f16* o = (blockIdx.y == 0) ? qo : ko;
        const float sc = (blockIdx.y == 0) ? QSCALE : 1.0f;
        #pragma unroll
        for (int i = 0; i < 8; ++i) {
            f16x8 pk;
            #pragma unroll
            for (int j = 0; j < 8; ++j) pk[j] = (f16)((acc[i][j] + bvals[j]) * sc);
            *(f16x8*)(o + (size_t)(row0 + ty * 8 + i) * DQK + tx * 8) = pk;
        }
    }
}

// ---------------- Flash attention, f16 MFMA ----------------
// grid 256 blocks x 512 thr (8 waves). Block: 64 q-rows. Waves: (wq 0..1) x (wk 0..3).
// Wave = 32 q-rows (2 rf) x 32-kv slice of each 128-kv LDS tile; partials merged in LDS.
// K tile [128 kv][128 d] f16 and V^T tile [128 d][128 kv] f16 staged via global_load_lds,
// 16B-chunk XOR-swizzled (chunk ^= row&7) through pre-swizzled global source addresses.

__device__ __forceinline__ void stage16(const void* g, unsigned char* l) {
    __builtin_amdgcn_global_load_lds(
        (const __attribute__((address_space(1))) unsigned int*)g,
        (__attribute__((address_space(3))) unsigned int*)l, 16, 0, 0);
}

#define KOFF 0u
#define VOFF 65536u
#define POFF 131072u
#define MOFF 151552u
#define LOFF 152576u

__global__ __launch_bounds__(512, 2) void attn_kernel(
    const f16* __restrict__ qg, const f16* __restrict__ kg,
    const f16* __restrict__ vtg, float* __restrict__ out)
{
    __shared__ __align__(16) unsigned char smem[153600];

    const int tid  = threadIdx.x;
    const int lane = tid & 63;
    const int w    = tid >> 6;      // 0..7
    const int wq   = w >> 2;        // 0..1
    const int wk   = w & 3;         // 0..3
    const int c    = lane & 15;
    const int g    = lane >> 4;     // 0..3

    // XCD-aware swizzle: each XCD pair handles one batch (K/V L2-resident)
    const int bid = blockIdx.x;
    const int xcd = bid & 7;
    const int bb  = xcd >> 1;
    const int qt  = (bid >> 3) | ((xcd & 1) << 5);
    const int q0  = qt * 64;

    const f16*  qb = qg  + (size_t)bb * SEQ * DQK;
    const char* kB = (const char*)(kg  + (size_t)bb * SEQ * DQK);
    const char* vB = (const char*)(vtg + (size_t)bb * DQK * SEQ);

    // Q A-frags: row = lane&15, k = (lane>>4)*8+i
    f16x8 qf[2][4];
    {
        const f16* qr = qb + (size_t)(q0 + wq * 32) * DQK;
        #pragma unroll
        for (int rf = 0; rf < 2; ++rf)
            #pragma unroll
            for (int ks = 0; ks < 4; ++ks)
                qf[rf][ks] = *(const f16x8*)(qr + (rf * 16 + c) * DQK + ks * 32 + 8 * g);
    }

    f32x4 o[2][9];   // [rf][d-frag 0..7, 8 = ones column = running l]
    #pragma unroll
    for (int rf = 0; rf < 2; ++rf)
        #pragma unroll
        for (int n = 0; n < 9; ++n) o[rf][n] = (f32x4)0.f;
    float m_run[2][4];
    #pragma unroll
    for (int rf = 0; rf < 2; ++rf)
        #pragma unroll
        for (int r = 0; r < 4; ++r) m_run[rf][r] = -3e38f;

    f16x8 onesf;
    #pragma unroll
    for (int i = 0; i < 8; ++i) onesf[i] = (f16)1.0f;

    const unsigned wbase = (unsigned)(tid >> 6) * 1024;

    auto stage_tiles = [&](int t, int pbuf) {
        const int kv0 = t * 128;
        unsigned char* kdst = smem + KOFF + (unsigned)pbuf * 32768u + wbase;
        unsigned char* vdst = smem + VOFF + (unsigned)pbuf * 32768u + wbase;
        #pragma unroll
        for (int cc = 0; cc < 4; ++cc) {
            const int j   = tid + cc * 512;
            const int row = j >> 4;
            const int col = j & 15;
            const int sw  = (col ^ (row & 7)) * 16;
            stage16(kB + (size_t)(kv0 + row) * 256 + sw, kdst + cc * 8192);
            stage16(vB + (size_t)row * 8192 + (size_t)kv0 * 2 + sw, vdst + cc * 8192);
        }
    };

    stage_tiles(0, 0);
    __syncthreads();   // drains vmcnt -> tile 0 ready

    unsigned char* const pmine = smem + POFF + (unsigned)w * 2560u;

    for (int t = 0; t < 32; ++t) {
        const int pb = t & 1;
        if (t < 31) stage_tiles(t + 1, pb ^ 1);

        unsigned char* const kbase = smem + KOFF + (unsigned)pb * 32768u;
        unsigned char* const vbase = smem + VOFF + (unsigned)pb * 32768u;

        // ---- QK^T: S[32 q][32 kv] per wave (pre-scaled, log2 domain) ----
        f32x4 s[2][2];
        s[0][0] = (f32x4)0.f; s[0][1] = (f32x4)0.f;
        s[1][0] = (f32x4)0.f; s[1][1] = (f32x4)0.f;
        #pragma unroll
        for (int ks = 0; ks < 4; ++ks) {
            #pragma unroll
            for (int n = 0; n < 2; ++n) {
                f16x8 bf = *(const f16x8*)(kbase
                    + (unsigned)(wk * 32 + n * 16 + c) * 256u
                    + (unsigned)(((4 * ks + g) ^ (c & 7)) * 16));
                s[0][n] = __builtin_amdgcn_mfma_f32_16x16x32_f16(qf[0][ks], bf, s[0][n], 0, 0, 0);
                s[1][n] = __builtin_amdgcn_mfma_f32_16x16x32_f16(qf[1][ks], bf, s[1][n], 0, 0, 0);
            }
        }

        // ---- online softmax (rows: rf*16 + 4g + r, shared across 16 c-lanes) ----
        float al[2][4];
        #pragma unroll
        for (int rf = 0; rf < 2; ++rf) {
            #pragma unroll
            for (int r = 0; r < 4; ++r) {
                float mt = fmaxf(s[rf][0][r], s[rf][1][r]);
                mt = fmaxf(mt, __shfl_xor(mt, 1, 16));
                mt = fmaxf(mt, __shfl_xor(mt, 2, 16));
                mt = fmaxf(mt, __shfl_xor(mt, 4, 16));
                mt = fmaxf(mt, __shfl_xor(mt, 8, 16));
                float mn = fmaxf(m_run[rf][r], mt);
                al[rf][r] = __builtin_amdgcn_exp2f(m_run[rf][r] - mn);
                m_run[rf][r] = mn;
            }
        }
        #pragma unroll
        for (int rf = 0; rf < 2; ++rf)
            #pragma unroll
            for (int n = 0; n < 9; ++n)
                #pragma unroll
                for (int r = 0; r < 4; ++r) o[rf][n][r] *= al[rf][r];

        // P = exp2(s - m), f16, to per-wave LDS [32 rows][stride 40 f16]
        f16* const pw = (f16*)pmine;
        #pragma unroll
        for (int rf = 0; rf < 2; ++rf)
            #pragma unroll
            for (int n = 0; n < 2; ++n)
                #pragma unroll
                for (int r = 0; r < 4; ++r) {
                    float pv = __builtin_amdgcn_exp2f(s[rf][n][r] - m_run[rf][r]);
                    pw[(rf * 16 + 4 * g + r) * 40 + n * 16 + c] = (f16)pv;
                }

        // ---- PV: O[32 q][128 d] += P[32 q][32 kv] * V[32 kv][128 d] ----
        f16x8 pa[2];
        pa[0] = *(const f16x8*)(pmine + (unsigned)(c) * 80u + 16u * g);
        pa[1] = *(const f16x8*)(pmine + (unsigned)(16 + c) * 80u + 16u * g);
        #pragma unroll
        for (int n = 0; n < 8; ++n) {
            f16x8 vf = *(const f16x8*)(vbase
                + (unsigned)(n * 16 + c) * 256u
                + (unsigned)(((4 * wk + g) ^ (c & 7)) * 16));
            o[0][n] = __builtin_amdgcn_mfma_f32_16x16x32_f16(pa[0], vf, o[0][n], 0, 0, 0);
            o[1][n] = __builtin_amdgcn_mfma_f32_16x16x32_f16(pa[1], vf, o[1][n], 0, 0, 0);
        }
        o[0][8] = __builtin_amdgcn_mfma_f32_16x16x32_f16(pa[0], onesf, o[0][8], 0, 0, 0);
        o[1][8] = __builtin_amdgcn_mfma_f32_16x16x32_f16(pa[1], onesf, o[1][8], 0, 0, 0);

        __syncthreads();   // staged next tile landed; this tile's reads done
    }

    // ---- merge the 4 kv-splits (per wq) via LDS ----
    float* const mld  = (float*)(smem + MOFF);
    float* const lld  = (float*)(smem + LOFF);
    float* const olds = (float*)smem;   // [wq][wk-1][32][132], reuses K/V buffers

    if (wk > 0) {
        const int base = (wq * 3 + (wk - 1)) * 32;
        #pragma unroll
        for (int rf = 0; rf < 2; ++rf)
            #pragma unroll
            for (int n = 0; n < 8; ++n)
                #pragma unroll
                for (int r = 0; r < 4; ++r)
                    olds[(size_t)(base + rf * 16 + 4 * g + r) * 132 + n * 16 + c] = o[rf][n][r];
        if (c == 0) {
            #pragma unroll
            for (int rf = 0; rf < 2; ++rf)
                #pragma unroll
                for (int r = 0; r < 4; ++r) {
                    mld[(wq * 4 + wk) * 32 + rf * 16 + 4 * g + r] = m_run[rf][r];
                    lld[(wq * 4 + wk) * 32 + rf * 16 + 4 * g + r] = o[rf][8][r];
                }
        }
    }
    __syncthreads();

    if (wk == 0) {
        #pragma unroll
        for (int rf = 0; rf < 2; ++rf) {
            #pragma unroll
            for (int r = 0; r < 4; ++r) {
                const int rl = rf * 16 + 4 * g + r;
                const float m0 = m_run[rf][r];
                const float m1 = mld[(wq * 4 + 1) * 32 + rl];
                const float m2 = mld[(wq * 4 + 2) * 32 + rl];
                const float m3 = mld[(wq * 4 + 3) * 32 + rl];
                const float ms = fmaxf(fmaxf(m0, m1), fmaxf(m2, m3));
                const float a0 = __builtin_amdgcn_exp2f(m0 - ms);
                const float a1 = __builtin_amdgcn_exp2f(m1 - ms);
                const float a2 = __builtin_amdgcn_exp2f(m2 - ms);
                const float a3 = __builtin_amdgcn_exp2f(m3 - ms);
                const float ls = a0 * o[rf][8][r]
                               + a1 * lld[(wq * 4 + 1) * 32 + rl]
                               + a2 * lld[(wq * 4 + 2) * 32 + rl]
                               + a3 * lld[(wq * 4 + 3) * 32 + rl];
                const float inv = 1.0f / ls;
                float* orow = out + ((size_t)bb * SEQ + q0 + wq * 32 + rl) * DQK;
                #pragma unroll
                for (int n = 0; n < 8; ++n) {
                    float v = a0 * o[rf][n][r]
                            + a1 * olds[(size_t)((wq * 3 + 0) * 32 + rl) * 132 + n * 16 + c]
                            + a2 * olds[(size_t)((wq * 3 + 1) * 32 + rl) * 132 + n * 16 + c]
                            + a3 * olds[(size_t)((wq * 3 + 2) * 32 + rl) * 132 + n * 16 + c];
                    orow[n * 16 + c] = v * inv;
                }
            }
        }
    }
}

extern "C" void kernel_launch(void* const* d_in, const int* in_sizes, int n_in,
                              void* d_out, int out_size, void* d_ws, size_t ws_size,
                              hipStream_t stream) {
    const float* x  = (const float*)d_in[0];
    const float* Wq = (const float*)d_in[1];
    const float* bq = (const float*)d_in[2];
    const float* Wk = (const float*)d_in[3];
    const float* bk = (const float*)d_in[4];
    const float* Wv = (const float*)d_in[5];
    const float* bv = (const float*)d_in[6];
    float* outp = (float*)d_out;

    f16* qf = (f16*)d_ws;                              // 4 MB
    f16* kf = qf + (size_t)BATCH * SEQ * DQK;          // 4 MB
    f16* vt = kf + (size_t)BATCH * SEQ * DQK;          // 4 MB (transposed [b][d][s])

    dim3 pgrid(BATCH * SEQ / 64, 3);
    proj_kernel<<<pgrid, 128, 0, stream>>>(x, Wq, bq, Wk, bk, Wv, bv, qf, kf, vt);

    attn_kernel<<<256, 512, 0, stream>>>(qf, kf, vt, outp);
}

// Round 3
// 123.793 us; speedup vs baseline: 7.2377x; 2.7021x over previous
//
#include <hip/hip_runtime.h>
#include <math.h>

#define DM    1024
#define DQK   128
#define BATCH 4
#define SEQ   4096
// 1/sqrt(128) * log2(e) folded into Wq/bq at wcvt time -> softmax uses exp2 directly
#define QSCALE (0.08838834764831845f * 1.4426950408889634f)

typedef _Float16 f16;
typedef _Float16 f16x8 __attribute__((ext_vector_type(8)));
typedef float    f32x4 __attribute__((ext_vector_type(4)));

// ---------------- W convert/transpose pre-kernel ----------------
// Wt[n][k] f16, n: 0..127=Q(scaled), 128..255=K, 256..383=V. biasf[n] fp32 (scaled).
__global__ __launch_bounds__(256) void wcvt_kernel(
    const float* __restrict__ Wq, const float* __restrict__ bq,
    const float* __restrict__ Wk, const float* __restrict__ bk,
    const float* __restrict__ Wv, const float* __restrict__ bv,
    f16* __restrict__ wt, float* __restrict__ biasf)
{
    const int n   = blockIdx.x;        // 0..383
    const int sel = n >> 7;
    const int nl  = n & 127;
    const float* W; const float* b; float sc;
    if (sel == 0)      { W = Wq; b = bq; sc = QSCALE; }
    else if (sel == 1) { W = Wk; b = bk; sc = 1.0f; }
    else               { W = Wv; b = bv; sc = 1.0f; }

    #pragma unroll
    for (int it = 0; it < 4; ++it) {
        int k = threadIdx.x + it * 256;
        wt[(size_t)n * DM + k] = (f16)(W[(size_t)k * DQK + nl] * sc);
    }
    if (threadIdx.x == 0) biasf[n] = b[nl] * sc;
}

// ---------------- Fused QKV projection, f16 MFMA ----------------
// 256 blocks x 512 thr (8 waves). Block: 64 rows x 384 cols (Q|K|V).
// Wave w = col-group: 64 rows x 48 cols (rf=4 x nf=3), 16x16x32 MFMA.
// x chunk [64 rows][64 k] fp32->f16 reg-staged into XOR-swizzled LDS, double-buffered,
// loads issued 2 chunks ahead. W frags read from global (L2-resident Wt).
// Epilogue bounces through padded LDS tile for coalesced Q/K/V^T stores.
__global__ __launch_bounds__(512, 2) void proj_kernel(
    const float* __restrict__ x, const f16* __restrict__ wt,
    const float* __restrict__ biasf,
    f16* __restrict__ qo, f16* __restrict__ ko, f16* __restrict__ vto)
{
    __shared__ __align__(16) unsigned char smem[50176];   // 2x8KB x-bufs, reused as 64x392 f16 tile

    const int tid  = threadIdx.x;
    const int lane = tid & 63;
    const int w    = tid >> 6;      // 0..7 col-group
    const int c    = lane & 15;
    const int g    = lane >> 4;     // 0..3
    const int r0   = blockIdx.x * 64;

    // staging role: thread -> (row, 8-f16 chunk)
    const int srow = tid >> 3;      // 0..63
    const int skq  = tid & 7;       // chunk 0..7
    const float* const xsrc  = x + (size_t)(r0 + srow) * DM + skq * 8;
    const unsigned     swoff = (unsigned)(srow * 128 + ((skq ^ (srow & 7)) * 16));

    f32x4 acc[4][3];
    #pragma unroll
    for (int rf = 0; rf < 4; ++rf)
        #pragma unroll
        for (int nf = 0; nf < 3; ++nf) acc[rf][nf] = (f32x4)0.f;

    float4 xa, xb2;
    auto gload = [&](int t) {
        const float* p = xsrc + t * 64;
        xa  = *(const float4*)p;
        xb2 = *(const float4*)(p + 4);
    };
    auto swrite = [&](int buf) {
        f16x8 h;
        h[0] = (f16)xa.x;  h[1] = (f16)xa.y;  h[2] = (f16)xa.z;  h[3] = (f16)xa.w;
        h[4] = (f16)xb2.x; h[5] = (f16)xb2.y; h[6] = (f16)xb2.z; h[7] = (f16)xb2.w;
        *(f16x8*)(smem + (unsigned)buf * 8192u + swoff) = h;
    };

    gload(0); swrite(0);
    gload(1);
    __syncthreads();

    for (int t = 0; t < 16; ++t) {
        const int cur = t & 1;
        if (t < 15) swrite(cur ^ 1);      // chunk t+1 (loaded last iter)
        if (t < 14) gload(t + 2);         // prefetch 2 ahead

        // A-frags from swizzled LDS: row = rf*16+c, k = ks*32 + g*8
        f16x8 af[4][2];
        #pragma unroll
        for (int rf = 0; rf < 4; ++rf)
            #pragma unroll
            for (int ks = 0; ks < 2; ++ks)
                af[rf][ks] = *(const f16x8*)(smem + (unsigned)cur * 8192u
                    + (unsigned)((rf * 16 + c) * 128)
                    + (unsigned)((((4 * ks + g) ^ (c & 7)) * 16)));

        // B-frags from global Wt (L2): col = w*48 + nf*16 + c, k = t*64 + ks*32 + g*8
        #pragma unroll
        for (int nf = 0; nf < 3; ++nf) {
            #pragma unroll
            for (int ks = 0; ks < 2; ++ks) {
                f16x8 bf = *(const f16x8*)(wt
                    + (size_t)(w * 48 + nf * 16 + c) * DM + t * 64 + ks * 32 + g * 8);
                #pragma unroll
                for (int rf = 0; rf < 4; ++rf)
                    acc[rf][nf] = __builtin_amdgcn_mfma_f32_16x16x32_f16(
                        af[rf][ks], bf, acc[rf][nf], 0, 0, 0);
            }
        }
        __syncthreads();
    }

    // ---- epilogue: bias + f16, bounce through LDS tile [64][392] for coalesced stores ----
    f16* const tile = (f16*)smem;
    #pragma unroll
    for (int rf = 0; rf < 4; ++rf)
        #pragma unroll
        for (int nf = 0; nf < 3; ++nf) {
            const int n  = w * 48 + nf * 16 + c;
            const float bb = biasf[n];
            #pragma unroll
            for (int r = 0; r < 4; ++r) {
                const int row = rf * 16 + 4 * g + r;
                tile[row * 392 + n] = (f16)(acc[rf][nf][r] + bb);
            }
        }
    __syncthreads();

    // Q, K: row-major coalesced
    #pragma unroll
    for (int it = 0; it < 2; ++it) {
        const int u   = tid + it * 512;
        const int row = u >> 4;
        const int c8  = (u & 15) * 8;
        *(f16x8*)(qo + (size_t)(r0 + row) * DQK + c8) = *(const f16x8*)&tile[row * 392 + c8];
        *(f16x8*)(ko + (size_t)(r0 + row) * DQK + c8) = *(const f16x8*)&tile[row * 392 + 128 + c8];
    }
    // V^T: vt[b][d][s], 16B per thread along s
    const int gb = r0 >> 12;
    const int s0 = r0 & (SEQ - 1);
    #pragma unroll
    for (int it = 0; it < 2; ++it) {
        const int u  = tid + it * 512;
        const int d  = u >> 3;
        const int s8 = (u & 7) * 8;
        f16x8 vv;
        #pragma unroll
        for (int i = 0; i < 8; ++i) vv[i] = tile[(s8 + i) * 392 + 256 + d];
        *(f16x8*)(vto + ((size_t)gb * DQK + d) * SEQ + s0 + s8) = vv;
    }
}

// ---------------- Flash attention, f16 MFMA (unchanged from round 2) ----------------
__device__ __forceinline__ void stage16(const void* g, unsigned char* l) {
    __builtin_amdgcn_global_load_lds(
        (const __attribute__((address_space(1))) unsigned int*)g,
        (__attribute__((address_space(3))) unsigned int*)l, 16, 0, 0);
}

#define KOFF 0u
#define VOFF 65536u
#define POFF 131072u
#define MOFF 151552u
#define LOFF 152576u

__global__ __launch_bounds__(512, 2) void attn_kernel(
    const f16* __restrict__ qg, const f16* __restrict__ kg,
    const f16* __restrict__ vtg, float* __restrict__ out)
{
    __shared__ __align__(16) unsigned char smem[153600];

    const int tid  = threadIdx.x;
    const int lane = tid & 63;
    const int w    = tid >> 6;      // 0..7
    const int wq   = w >> 2;        // 0..1
    const int wk   = w & 3;         // 0..3
    const int c    = lane & 15;
    const int g    = lane >> 4;     // 0..3

    const int bid = blockIdx.x;
    const int xcd = bid & 7;
    const int bb  = xcd >> 1;
    const int qt  = (bid >> 3) | ((xcd & 1) << 5);
    const int q0  = qt * 64;

    const f16*  qb = qg  + (size_t)bb * SEQ * DQK;
    const char* kB = (const char*)(kg  + (size_t)bb * SEQ * DQK);
    const char* vB = (const char*)(vtg + (size_t)bb * DQK * SEQ);

    f16x8 qf[2][4];
    {
        const f16* qr = qb + (size_t)(q0 + wq * 32) * DQK;
        #pragma unroll
        for (int rf = 0; rf < 2; ++rf)
            #pragma unroll
            for (int ks = 0; ks < 4; ++ks)
                qf[rf][ks] = *(const f16x8*)(qr + (rf * 16 + c) * DQK + ks * 32 + 8 * g);
    }

    f32x4 o[2][9];
    #pragma unroll
    for (int rf = 0; rf < 2; ++rf)
        #pragma unroll
        for (int n = 0; n < 9; ++n) o[rf][n] = (f32x4)0.f;
    float m_run[2][4];
    #pragma unroll
    for (int rf = 0; rf < 2; ++rf)
        #pragma unroll
        for (int r = 0; r < 4; ++r) m_run[rf][r] = -3e38f;

    f16x8 onesf;
    #pragma unroll
    for (int i = 0; i < 8; ++i) onesf[i] = (f16)1.0f;

    const unsigned wbase = (unsigned)(tid >> 6) * 1024;

    auto stage_tiles = [&](int t, int pbuf) {
        const int kv0 = t * 128;
        unsigned char* kdst = smem + KOFF + (unsigned)pbuf * 32768u + wbase;
        unsigned char* vdst = smem + VOFF + (unsigned)pbuf * 32768u + wbase;
        #pragma unroll
        for (int cc = 0; cc < 4; ++cc) {
            const int j   = tid + cc * 512;
            const int row = j >> 4;
            const int col = j & 15;
            const int sw  = (col ^ (row & 7)) * 16;
            stage16(kB + (size_t)(kv0 + row) * 256 + sw, kdst + cc * 8192);
            stage16(vB + (size_t)row * 8192 + (size_t)kv0 * 2 + sw, vdst + cc * 8192);
        }
    };

    stage_tiles(0, 0);
    __syncthreads();

    unsigned char* const pmine = smem + POFF + (unsigned)w * 2560u;

    for (int t = 0; t < 32; ++t) {
        const int pb = t & 1;
        if (t < 31) stage_tiles(t + 1, pb ^ 1);

        unsigned char* const kbase = smem + KOFF + (unsigned)pb * 32768u;
        unsigned char* const vbase = smem + VOFF + (unsigned)pb * 32768u;

        f32x4 s[2][2];
        s[0][0] = (f32x4)0.f; s[0][1] = (f32x4)0.f;
        s[1][0] = (f32x4)0.f; s[1][1] = (f32x4)0.f;
        #pragma unroll
        for (int ks = 0; ks < 4; ++ks) {
            #pragma unroll
            for (int n = 0; n < 2; ++n) {
                f16x8 bf = *(const f16x8*)(kbase
                    + (unsigned)(wk * 32 + n * 16 + c) * 256u
                    + (unsigned)(((4 * ks + g) ^ (c & 7)) * 16));
                s[0][n] = __builtin_amdgcn_mfma_f32_16x16x32_f16(qf[0][ks], bf, s[0][n], 0, 0, 0);
                s[1][n] = __builtin_amdgcn_mfma_f32_16x16x32_f16(qf[1][ks], bf, s[1][n], 0, 0, 0);
            }
        }

        float al[2][4];
        #pragma unroll
        for (int rf = 0; rf < 2; ++rf) {
            #pragma unroll
            for (int r = 0; r < 4; ++r) {
                float mt = fmaxf(s[rf][0][r], s[rf][1][r]);
                mt = fmaxf(mt, __shfl_xor(mt, 1, 16));
                mt = fmaxf(mt, __shfl_xor(mt, 2, 16));
                mt = fmaxf(mt, __shfl_xor(mt, 4, 16));
                mt = fmaxf(mt, __shfl_xor(mt, 8, 16));
                float mn = fmaxf(m_run[rf][r], mt);
                al[rf][r] = __builtin_amdgcn_exp2f(m_run[rf][r] - mn);
                m_run[rf][r] = mn;
            }
        }
        #pragma unroll
        for (int rf = 0; rf < 2; ++rf)
            #pragma unroll
            for (int n = 0; n < 9; ++n)
                #pragma unroll
                for (int r = 0; r < 4; ++r) o[rf][n][r] *= al[rf][r];

        f16* const pw = (f16*)pmine;
        #pragma unroll
        for (int rf = 0; rf < 2; ++rf)
            #pragma unroll
            for (int n = 0; n < 2; ++n)
                #pragma unroll
                for (int r = 0; r < 4; ++r) {
                    float pv = __builtin_amdgcn_exp2f(s[rf][n][r] - m_run[rf][r]);
                    pw[(rf * 16 + 4 * g + r) * 40 + n * 16 + c] = (f16)pv;
                }

        f16x8 pa[2];
        pa[0] = *(const f16x8*)(pmine + (unsigned)(c) * 80u + 16u * g);
        pa[1] = *(const f16x8*)(pmine + (unsigned)(16 + c) * 80u + 16u * g);
        #pragma unroll
        for (int n = 0; n < 8; ++n) {
            f16x8 vf = *(const f16x8*)(vbase
                + (unsigned)(n * 16 + c) * 256u
                + (unsigned)(((4 * wk + g) ^ (c & 7)) * 16));
            o[0][n] = __builtin_amdgcn_mfma_f32_16x16x32_f16(pa[0], vf, o[0][n], 0, 0, 0);
            o[1][n] = __builtin_amdgcn_mfma_f32_16x16x32_f16(pa[1], vf, o[1][n], 0, 0, 0);
        }
        o[0][8] = __builtin_amdgcn_mfma_f32_16x16x32_f16(pa[0], onesf, o[0][8], 0, 0, 0);
        o[1][8] = __builtin_amdgcn_mfma_f32_16x16x32_f16(pa[1], onesf, o[1][8], 0, 0, 0);

        __syncthreads();
    }

    float* const mld  = (float*)(smem + MOFF);
    float* const lld  = (float*)(smem + LOFF);
    float* const olds = (float*)smem;

    if (wk > 0) {
        const int base = (wq * 3 + (wk - 1)) * 32;
        #pragma unroll
        for (int rf = 0; rf < 2; ++rf)
            #pragma unroll
            for (int n = 0; n < 8; ++n)
                #pragma unroll
                for (int r = 0; r < 4; ++r)
                    olds[(size_t)(base + rf * 16 + 4 * g + r) * 132 + n * 16 + c] = o[rf][n][r];
        if (c == 0) {
            #pragma unroll
            for (int rf = 0; rf < 2; ++rf)
                #pragma unroll
                for (int r = 0; r < 4; ++r) {
                    mld[(wq * 4 + wk) * 32 + rf * 16 + 4 * g + r] = m_run[rf][r];
                    lld[(wq * 4 + wk) * 32 + rf * 16 + 4 * g + r] = o[rf][8][r];
                }
        }
    }
    __syncthreads();

    if (wk == 0) {
        #pragma unroll
        for (int rf = 0; rf < 2; ++rf) {
            #pragma unroll
            for (int r = 0; r < 4; ++r) {
                const int rl = rf * 16 + 4 * g + r;
                const float m0 = m_run[rf][r];
                const float m1 = mld[(wq * 4 + 1) * 32 + rl];
                const float m2 = mld[(wq * 4 + 2) * 32 + rl];
                const float m3 = mld[(wq * 4 + 3) * 32 + rl];
                const float ms = fmaxf(fmaxf(m0, m1), fmaxf(m2, m3));
                const float a0 = __builtin_amdgcn_exp2f(m0 - ms);
                const float a1 = __builtin_amdgcn_exp2f(m1 - ms);
                const float a2 = __builtin_amdgcn_exp2f(m2 - ms);
                const float a3 = __builtin_amdgcn_exp2f(m3 - ms);
                const float ls = a0 * o[rf][8][r]
                               + a1 * lld[(wq * 4 + 1) * 32 + rl]
                               + a2 * lld[(wq * 4 + 2) * 32 + rl]
                               + a3 * lld[(wq * 4 + 3) * 32 + rl];
                const float inv = 1.0f / ls;
                float* orow = out + ((size_t)bb * SEQ + q0 + wq * 32 + rl) * DQK;
                #pragma unroll
                for (int n = 0; n < 8; ++n) {
                    float v = a0 * o[rf][n][r]
                            + a1 * olds[(size_t)((wq * 3 + 0) * 32 + rl) * 132 + n * 16 + c]
                            + a2 * olds[(size_t)((wq * 3 + 1) * 32 + rl) * 132 + n * 16 + c]
                            + a3 * olds[(size_t)((wq * 3 + 2) * 32 + rl) * 132 + n * 16 + c];
                    orow[n * 16 + c] = v * inv;
                }
            }
        }
    }
}

extern "C" void kernel_launch(void* const* d_in, const int* in_sizes, int n_in,
                              void* d_out, int out_size, void* d_ws, size_t ws_size,
                              hipStream_t stream) {
    const float* x  = (const float*)d_in[0];
    const float* Wq = (const float*)d_in[1];
    const float* bq = (const float*)d_in[2];
    const float* Wk = (const float*)d_in[3];
    const float* bk = (const float*)d_in[4];
    const float* Wv = (const float*)d_in[5];
    const float* bv = (const float*)d_in[6];
    float* outp = (float*)d_out;

    f16*   qf    = (f16*)d_ws;                           // 4 MB
    f16*   kf    = qf + (size_t)BATCH * SEQ * DQK;       // 4 MB
    f16*   vt    = kf + (size_t)BATCH * SEQ * DQK;       // 4 MB (transposed [b][d][s])
    f16*   wt    = vt + (size_t)BATCH * DQK * SEQ;       // 768 KB
    float* biasf = (float*)(wt + (size_t)384 * DM);      // 1.5 KB

    wcvt_kernel<<<384, 256, 0, stream>>>(Wq, bq, Wk, bk, Wv, bv, wt, biasf);

    proj_kernel<<<BATCH * SEQ / 64, 512, 0, stream>>>(x, wt, biasf, qf, kf, vt);

    attn_kernel<<<256, 512, 0, stream>>>(qf, kf, vt, outp);
}

// Round 4
// 101.110 us; speedup vs baseline: 8.8614x; 1.2243x over previous
//
#include <hip/hip_runtime.h>
#include <math.h>

#define DM    1024
#define DQK   128
#define BATCH 4
#define SEQ   4096
// 1/sqrt(128) * log2(e) folded into Wq/bq at wcvt time -> softmax uses exp2 directly
#define QSCALE (0.08838834764831845f * 1.4426950408889634f)
#define DEFER_THR 6.0f

typedef _Float16 f16;
typedef _Float16 f16x4 __attribute__((ext_vector_type(4)));
typedef _Float16 f16x8 __attribute__((ext_vector_type(8)));
typedef float    f32x4 __attribute__((ext_vector_type(4)));

// ---------------- W convert/transpose pre-kernel ----------------
// Wt[n][k] f16, n: 0..127=Q(scaled), 128..255=K, 256..383=V. biasf[n] fp32 (scaled).
// grid 24 = 3 sel x 8 k-slabs; coalesced row loads, LDS transpose, coalesced f16x8 stores.
__global__ __launch_bounds__(256) void wcvt_kernel(
    const float* __restrict__ Wq, const float* __restrict__ bq,
    const float* __restrict__ Wk, const float* __restrict__ bk,
    const float* __restrict__ Wv, const float* __restrict__ bv,
    f16* __restrict__ wt, float* __restrict__ biasf)
{
    const int sel = blockIdx.x >> 3;
    const int k0  = (blockIdx.x & 7) * 128;
    const float* W; const float* b; float sc;
    if (sel == 0)      { W = Wq; b = bq; sc = QSCALE; }
    else if (sel == 1) { W = Wk; b = bk; sc = 1.0f; }
    else               { W = Wv; b = bv; sc = 1.0f; }

    __shared__ f16 tile[128][136];

    #pragma unroll
    for (int it = 0; it < 16; ++it) {
        int flat = threadIdx.x + it * 256;   // 0..4095
        int kk   = flat >> 5;                 // 0..127
        int c4   = flat & 31;
        float4 w4 = *(const float4*)(W + (size_t)(k0 + kk) * DQK + c4 * 4);
        tile[kk][c4 * 4 + 0] = (f16)(w4.x * sc);
        tile[kk][c4 * 4 + 1] = (f16)(w4.y * sc);
        tile[kk][c4 * 4 + 2] = (f16)(w4.z * sc);
        tile[kk][c4 * 4 + 3] = (f16)(w4.w * sc);
    }
    __syncthreads();

    #pragma unroll
    for (int it = 0; it < 8; ++it) {
        int flat = threadIdx.x + it * 256;   // 0..2047
        int n    = flat >> 4;                 // 0..127
        int kc   = flat & 15;                 // 8-chunk
        f16x8 v;
        #pragma unroll
        for (int i = 0; i < 8; ++i) v[i] = tile[kc * 8 + i][n];
        *(f16x8*)(wt + (size_t)(sel * 128 + n) * DM + k0 + kc * 8) = v;
    }
    if ((blockIdx.x & 7) == 0 && threadIdx.x < 128)
        biasf[sel * 128 + threadIdx.x] = b[threadIdx.x] * sc;
}

// ---------------- Fused QKV projection, f16 MFMA (unchanged from round 3) ----------------
__global__ __launch_bounds__(512, 2) void proj_kernel(
    const float* __restrict__ x, const f16* __restrict__ wt,
    const float* __restrict__ biasf,
    f16* __restrict__ qo, f16* __restrict__ ko, f16* __restrict__ vto)
{
    __shared__ __align__(16) unsigned char smem[50176];

    const int tid  = threadIdx.x;
    const int lane = tid & 63;
    const int w    = tid >> 6;
    const int c    = lane & 15;
    const int g    = lane >> 4;
    const int r0   = blockIdx.x * 64;

    const int srow = tid >> 3;
    const int skq  = tid & 7;
    const float* const xsrc  = x + (size_t)(r0 + srow) * DM + skq * 8;
    const unsigned     swoff = (unsigned)(srow * 128 + ((skq ^ (srow & 7)) * 16));

    f32x4 acc[4][3];
    #pragma unroll
    for (int rf = 0; rf < 4; ++rf)
        #pragma unroll
        for (int nf = 0; nf < 3; ++nf) acc[rf][nf] = (f32x4)0.f;

    float4 xa, xb2;
    auto gload = [&](int t) {
        const float* p = xsrc + t * 64;
        xa  = *(const float4*)p;
        xb2 = *(const float4*)(p + 4);
    };
    auto swrite = [&](int buf) {
        f16x8 h;
        h[0] = (f16)xa.x;  h[1] = (f16)xa.y;  h[2] = (f16)xa.z;  h[3] = (f16)xa.w;
        h[4] = (f16)xb2.x; h[5] = (f16)xb2.y; h[6] = (f16)xb2.z; h[7] = (f16)xb2.w;
        *(f16x8*)(smem + (unsigned)buf * 8192u + swoff) = h;
    };

    gload(0); swrite(0);
    gload(1);
    __syncthreads();

    for (int t = 0; t < 16; ++t) {
        const int cur = t & 1;
        if (t < 15) swrite(cur ^ 1);
        if (t < 14) gload(t + 2);

        f16x8 af[4][2];
        #pragma unroll
        for (int rf = 0; rf < 4; ++rf)
            #pragma unroll
            for (int ks = 0; ks < 2; ++ks)
                af[rf][ks] = *(const f16x8*)(smem + (unsigned)cur * 8192u
                    + (unsigned)((rf * 16 + c) * 128)
                    + (unsigned)((((4 * ks + g) ^ (c & 7)) * 16)));

        #pragma unroll
        for (int nf = 0; nf < 3; ++nf) {
            #pragma unroll
            for (int ks = 0; ks < 2; ++ks) {
                f16x8 bf = *(const f16x8*)(wt
                    + (size_t)(w * 48 + nf * 16 + c) * DM + t * 64 + ks * 32 + g * 8);
                #pragma unroll
                for (int rf = 0; rf < 4; ++rf)
                    acc[rf][nf] = __builtin_amdgcn_mfma_f32_16x16x32_f16(
                        af[rf][ks], bf, acc[rf][nf], 0, 0, 0);
            }
        }
        __syncthreads();
    }

    f16* const tile = (f16*)smem;
    #pragma unroll
    for (int rf = 0; rf < 4; ++rf)
        #pragma unroll
        for (int nf = 0; nf < 3; ++nf) {
            const int n  = w * 48 + nf * 16 + c;
            const float bb = biasf[n];
            #pragma unroll
            for (int r = 0; r < 4; ++r) {
                const int row = rf * 16 + 4 * g + r;
                tile[row * 392 + n] = (f16)(acc[rf][nf][r] + bb);
            }
        }
    __syncthreads();

    #pragma unroll
    for (int it = 0; it < 2; ++it) {
        const int u   = tid + it * 512;
        const int row = u >> 4;
        const int c8  = (u & 15) * 8;
        *(f16x8*)(qo + (size_t)(r0 + row) * DQK + c8) = *(const f16x8*)&tile[row * 392 + c8];
        *(f16x8*)(ko + (size_t)(r0 + row) * DQK + c8) = *(const f16x8*)&tile[row * 392 + 128 + c8];
    }
    const int gb = r0 >> 12;
    const int s0 = r0 & (SEQ - 1);
    #pragma unroll
    for (int it = 0; it < 2; ++it) {
        const int u  = tid + it * 512;
        const int d  = u >> 3;
        const int s8 = (u & 7) * 8;
        f16x8 vv;
        #pragma unroll
        for (int i = 0; i < 8; ++i) vv[i] = tile[(s8 + i) * 392 + 256 + d];
        *(f16x8*)(vto + ((size_t)gb * DQK + d) * SEQ + s0 + s8) = vv;
    }
}

// ---------------- Flash attention, f16 MFMA, swapped QK^T + defer-max ----------------
__device__ __forceinline__ void stage16(const void* g, unsigned char* l) {
    __builtin_amdgcn_global_load_lds(
        (const __attribute__((address_space(1))) unsigned int*)g,
        (__attribute__((address_space(3))) unsigned int*)l, 16, 0, 0);
}

#define KOFF 0u
#define VOFF 65536u
#define POFF 131072u
#define MOFF 151552u
#define LOFF 152576u

__global__ __launch_bounds__(512, 2) void attn_kernel(
    const f16* __restrict__ qg, const f16* __restrict__ kg,
    const f16* __restrict__ vtg, float* __restrict__ out)
{
    __shared__ __align__(16) unsigned char smem[153600];

    const int tid  = threadIdx.x;
    const int lane = tid & 63;
    const int w    = tid >> 6;      // 0..7
    const int wq   = w >> 2;        // 0..1
    const int wk   = w & 3;         // 0..3
    const int c    = lane & 15;
    const int g    = lane >> 4;     // 0..3

    const int bid = blockIdx.x;
    const int xcd = bid & 7;
    const int bb  = xcd >> 1;
    const int qt  = (bid >> 3) | ((xcd & 1) << 5);
    const int q0  = qt * 64;

    const f16*  qb = qg  + (size_t)bb * SEQ * DQK;
    const char* kB = (const char*)(kg  + (size_t)bb * SEQ * DQK);
    const char* vB = (const char*)(vtg + (size_t)bb * DQK * SEQ);

    // Q frags (B-operand for swapped QK^T): q = 16n + c, k(d) = ks*32 + 8g + i
    f16x8 qf[2][4];
    {
        const f16* qr = qb + (size_t)(q0 + wq * 32) * DQK;
        #pragma unroll
        for (int n = 0; n < 2; ++n)
            #pragma unroll
            for (int ks = 0; ks < 4; ++ks)
                qf[n][ks] = *(const f16x8*)(qr + (n * 16 + c) * DQK + ks * 32 + 8 * g);
    }

    f32x4 o[2][9];   // [n (q-frag)][d-frag 0..7, 8 = ones column = running l]
    #pragma unroll
    for (int n = 0; n < 2; ++n)
        #pragma unroll
        for (int f = 0; f < 9; ++f) o[n][f] = (f32x4)0.f;
    float m_run[2] = {-3e38f, -3e38f};   // S^T domain: q = 16n + c

    f16x8 onesf;
    #pragma unroll
    for (int i = 0; i < 8; ++i) onesf[i] = (f16)1.0f;

    const unsigned wbase = (unsigned)(tid >> 6) * 1024;

    auto stage_tiles = [&](int t, int pbuf) {
        const int kv0 = t * 128;
        unsigned char* kdst = smem + KOFF + (unsigned)pbuf * 32768u + wbase;
        unsigned char* vdst = smem + VOFF + (unsigned)pbuf * 32768u + wbase;
        #pragma unroll
        for (int cc = 0; cc < 4; ++cc) {
            const int j   = tid + cc * 512;
            const int row = j >> 4;
            const int col = j & 15;
            const int sw  = (col ^ (row & 7)) * 16;
            stage16(kB + (size_t)(kv0 + row) * 256 + sw, kdst + cc * 8192);
            stage16(vB + (size_t)row * 8192 + (size_t)kv0 * 2 + sw, vdst + cc * 8192);
        }
    };

    stage_tiles(0, 0);
    __syncthreads();

    unsigned char* const pmine = smem + POFF + (unsigned)w * 2560u;

    for (int t = 0; t < 32; ++t) {
        const int pb = t & 1;
        if (t < 31) stage_tiles(t + 1, pb ^ 1);

        unsigned char* const kbase = smem + KOFF + (unsigned)pb * 32768u;
        unsigned char* const vbase = smem + VOFF + (unsigned)pb * 32768u;

        // ---- swapped QK^T: S^T[kv 32][q 32] per wave ----
        // A = K frag (row kv = wk*32 + 16m + c), B = Q frag. C: col=q=c (+16n), row kv=4g+r (+16m)
        f32x4 s[2][2];   // [m (kv16)][n (q16)]
        s[0][0] = (f32x4)0.f; s[0][1] = (f32x4)0.f;
        s[1][0] = (f32x4)0.f; s[1][1] = (f32x4)0.f;
        __builtin_amdgcn_s_setprio(1);
        #pragma unroll
        for (int ks = 0; ks < 4; ++ks) {
            #pragma unroll
            for (int m = 0; m < 2; ++m) {
                f16x8 kf = *(const f16x8*)(kbase
                    + (unsigned)(wk * 32 + m * 16 + c) * 256u
                    + (unsigned)(((4 * ks + g) ^ (c & 7)) * 16));
                s[m][0] = __builtin_amdgcn_mfma_f32_16x16x32_f16(kf, qf[0][ks], s[m][0], 0, 0, 0);
                s[m][1] = __builtin_amdgcn_mfma_f32_16x16x32_f16(kf, qf[1][ks], s[m][1], 0, 0, 0);
            }
        }
        __builtin_amdgcn_s_setprio(0);

        // ---- lane-local softmax max (per q-row = 16n + c) ----
        float mt[2];
        #pragma unroll
        for (int n = 0; n < 2; ++n) {
            float a0 = fmaxf(fmaxf(s[0][n][0], s[0][n][1]), fmaxf(s[0][n][2], s[0][n][3]));
            float a1 = fmaxf(fmaxf(s[1][n][0], s[1][n][1]), fmaxf(s[1][n][2], s[1][n][3]));
            float v  = fmaxf(a0, a1);
            v = fmaxf(v, __shfl_xor(v, 16, 64));
            v = fmaxf(v, __shfl_xor(v, 32, 64));
            mt[n] = v;
        }

        // ---- defer-max: rescale only when the running max grows past THR ----
        bool need = (mt[0] > m_run[0] + DEFER_THR) || (mt[1] > m_run[1] + DEFER_THR);
        if (__any(need)) {
            float al[2];
            #pragma unroll
            for (int n = 0; n < 2; ++n) {
                float mn = fmaxf(m_run[n], mt[n]);
                al[n] = __builtin_amdgcn_exp2f(m_run[n] - mn);
                m_run[n] = mn;
            }
            // ship alpha to O domain: O rows q = 16n + 4g + r  <-  S lanes c' = 4g + r
            float alo[2][4];
            #pragma unroll
            for (int n = 0; n < 2; ++n)
                #pragma unroll
                for (int r = 0; r < 4; ++r)
                    alo[n][r] = __shfl(al[n], 4 * g + r, 16);
            #pragma unroll
            for (int n = 0; n < 2; ++n)
                #pragma unroll
                for (int f = 0; f < 9; ++f)
                    #pragma unroll
                    for (int r = 0; r < 4; ++r) o[n][f][r] *= alo[n][r];
        }

        // ---- P = exp2(S^T - m), packed b64 stores: P[q = 16n+c][kv = 16m+4g .. +3] ----
        #pragma unroll
        for (int n = 0; n < 2; ++n)
            #pragma unroll
            for (int m = 0; m < 2; ++m) {
                f16x4 h;
                #pragma unroll
                for (int r = 0; r < 4; ++r)
                    h[r] = (f16)__builtin_amdgcn_exp2f(s[m][n][r] - m_run[n]);
                *(f16x4*)(pmine + (unsigned)(16 * n + c) * 80u + (unsigned)(32 * m + 8 * g)) = h;
            }

        // ---- PV: O[32 q][128 d] += P[32 q][32 kv] * V[32 kv][128 d] ----
        f16x8 pa[2];
        pa[0] = *(const f16x8*)(pmine + (unsigned)(c) * 80u + 16u * g);
        pa[1] = *(const f16x8*)(pmine + (unsigned)(16 + c) * 80u + 16u * g);
        __builtin_amdgcn_s_setprio(1);
        #pragma unroll
        for (int df = 0; df < 8; ++df) {
            f16x8 vf = *(const f16x8*)(vbase
                + (unsigned)(df * 16 + c) * 256u
                + (unsigned)(((4 * wk + g) ^ (c & 7)) * 16));
            o[0][df] = __builtin_amdgcn_mfma_f32_16x16x32_f16(pa[0], vf, o[0][df], 0, 0, 0);
            o[1][df] = __builtin_amdgcn_mfma_f32_16x16x32_f16(pa[1], vf, o[1][df], 0, 0, 0);
        }
        o[0][8] = __builtin_amdgcn_mfma_f32_16x16x32_f16(pa[0], onesf, o[0][8], 0, 0, 0);
        o[1][8] = __builtin_amdgcn_mfma_f32_16x16x32_f16(pa[1], onesf, o[1][8], 0, 0, 0);
        __builtin_amdgcn_s_setprio(0);

        __syncthreads();
    }

    // ship final m to O domain (q = 16n + 4g + r)
    float m_o[2][4];
    #pragma unroll
    for (int n = 0; n < 2; ++n)
        #pragma unroll
        for (int r = 0; r < 4; ++r)
            m_o[n][r] = __shfl(m_run[n], 4 * g + r, 16);

    // ---- merge the 4 kv-splits (per wq) via LDS ----
    float* const mld  = (float*)(smem + MOFF);
    float* const lld  = (float*)(smem + LOFF);
    float* const olds = (float*)smem;

    if (wk > 0) {
        const int base = (wq * 3 + (wk - 1)) * 32;
        #pragma unroll
        for (int n = 0; n < 2; ++n)
            #pragma unroll
            for (int f = 0; f < 8; ++f)
                #pragma unroll
                for (int r = 0; r < 4; ++r)
                    olds[(size_t)(base + n * 16 + 4 * g + r) * 132 + f * 16 + c] = o[n][f][r];
        if (c == 0) {
            #pragma unroll
            for (int n = 0; n < 2; ++n)
                #pragma unroll
                for (int r = 0; r < 4; ++r) {
                    mld[(wq * 4 + wk) * 32 + n * 16 + 4 * g + r] = m_o[n][r];
                    lld[(wq * 4 + wk) * 32 + n * 16 + 4 * g + r] = o[n][8][r];
                }
        }
    }
    __syncthreads();

    if (wk == 0) {
        #pragma unroll
        for (int n = 0; n < 2; ++n) {
            #pragma unroll
            for (int r = 0; r < 4; ++r) {
                const int rl = n * 16 + 4 * g + r;
                const float m0 = m_o[n][r];
                const float m1 = mld[(wq * 4 + 1) * 32 + rl];
                const float m2 = mld[(wq * 4 + 2) * 32 + rl];
                const float m3 = mld[(wq * 4 + 3) * 32 + rl];
                const float ms = fmaxf(fmaxf(m0, m1), fmaxf(m2, m3));
                const float a0 = __builtin_amdgcn_exp2f(m0 - ms);
                const float a1 = __builtin_amdgcn_exp2f(m1 - ms);
                const float a2 = __builtin_amdgcn_exp2f(m2 - ms);
                const float a3 = __builtin_amdgcn_exp2f(m3 - ms);
                const float ls = a0 * o[n][8][r]
                               + a1 * lld[(wq * 4 + 1) * 32 + rl]
                               + a2 * lld[(wq * 4 + 2) * 32 + rl]
                               + a3 * lld[(wq * 4 + 3) * 32 + rl];
                const float inv = 1.0f / ls;
                float* orow = out + ((size_t)bb * SEQ + q0 + wq * 32 + rl) * DQK;
                #pragma unroll
                for (int f = 0; f < 8; ++f) {
                    float v = a0 * o[n][f][r]
                            + a1 * olds[(size_t)((wq * 3 + 0) * 32 + rl) * 132 + f * 16 + c]
                            + a2 * olds[(size_t)((wq * 3 + 1) * 32 + rl) * 132 + f * 16 + c]
                            + a3 * olds[(size_t)((wq * 3 + 2) * 32 + rl) * 132 + f * 16 + c];
                    orow[f * 16 + c] = v * inv;
                }
            }
        }
    }
}

extern "C" void kernel_launch(void* const* d_in, const int* in_sizes, int n_in,
                              void* d_out, int out_size, void* d_ws, size_t ws_size,
                              hipStream_t stream) {
    const float* x  = (const float*)d_in[0];
    const float* Wq = (const float*)d_in[1];
    const float* bq = (const float*)d_in[2];
    const float* Wk = (const float*)d_in[3];
    const float* bk = (const float*)d_in[4];
    const float* Wv = (const float*)d_in[5];
    const float* bv = (const float*)d_in[6];
    float* outp = (float*)d_out;

    f16*   qf    = (f16*)d_ws;                           // 4 MB
    f16*   kf    = qf + (size_t)BATCH * SEQ * DQK;       // 4 MB
    f16*   vt    = kf + (size_t)BATCH * SEQ * DQK;       // 4 MB (transposed [b][d][s])
    f16*   wt    = vt + (size_t)BATCH * DQK * SEQ;       // 768 KB
    float* biasf = (float*)(wt + (size_t)384 * DM);      // 1.5 KB

    wcvt_kernel<<<24, 256, 0, stream>>>(Wq, bq, Wk, bk, Wv, bv, wt, biasf);

    proj_kernel<<<BATCH * SEQ / 64, 512, 0, stream>>>(x, wt, biasf, qf, kf, vt);

    attn_kernel<<<256, 512, 0, stream>>>(qf, kf, vt, outp);
}